// Round 2
// baseline (585.317 us; speedup 1.0000x reference)
//
#include <hip/hip_runtime.h>
#include <hip/hip_bf16.h>

#define N_NODES 50000
#define N_EDGES 800000
#define F_IN    128
#define NH      4
#define F_OUTD  64
#define C_OUT   256   // NH*F_OUTD

typedef short bf16x8 __attribute__((ext_vector_type(8)));
typedef float f32x4  __attribute__((ext_vector_type(4)));

__device__ __forceinline__ float bf2f(unsigned short u) {
    union { unsigned int i; float f; } v; v.i = ((unsigned int)u) << 16; return v.f;
}
__device__ __forceinline__ unsigned short f2bf(float f) {
    union { float f; unsigned int u; } v; v.f = f;
    unsigned int r = (v.u + 0x7FFFu + ((v.u >> 16) & 1u)) >> 16;
    return (unsigned short)r;
}

// ---------------- f32 -> bf16 conversion of feat and fc_w ----------------
__global__ __launch_bounds__(256) void k_cvt(const float* __restrict__ feat,
                                             const float* __restrict__ fcw,
                                             unsigned short* __restrict__ fb16,
                                             unsigned short* __restrict__ wb16) {
    int i = blockIdx.x * 256 + threadIdx.x;   // one float4 per thread
    const int NF = N_NODES * F_IN / 4;        // 1,600,000
    const int NW = C_OUT * F_IN / 4;          // 8,192
    if (i < NF) {
        float4 v = ((const float4*)feat)[i];
        ushort4 o = { f2bf(v.x), f2bf(v.y), f2bf(v.z), f2bf(v.w) };
        ((ushort4*)fb16)[i] = o;
    } else if (i < NF + NW) {
        int j = i - NF;
        float4 v = ((const float4*)fcw)[j];
        ushort4 o = { f2bf(v.x), f2bf(v.y), f2bf(v.z), f2bf(v.w) };
        ((ushort4*)wb16)[j] = o;
    }
}

// ---------------- ft = feat @ fc_w.T  (bf16 MFMA, M=50000=3125*16, N=256, K=128) ---
__global__ __launch_bounds__(256) void k_ft(const unsigned short* __restrict__ fb16,
                                            const unsigned short* __restrict__ wb16,
                                            unsigned short* __restrict__ ftb) {
    int t = threadIdx.x;
    int wave = blockIdx.x * 4 + (t >> 6);
    if (wave >= 3125) return;
    int lane = t & 63, r = lane & 15, q = lane >> 4;
    int m0 = wave * 16;
    f32x4 acc[16] = {};
    const bf16x8* A = (const bf16x8*)fb16;
    const bf16x8* B = (const bf16x8*)wb16;
#pragma unroll
    for (int ks = 0; ks < 4; ++ks) {
        bf16x8 a = A[(size_t)(m0 + r) * 16 + ks * 4 + q];
#pragma unroll
        for (int ct = 0; ct < 16; ++ct) {
            int col = ct * 16 + r;
            bf16x8 b = B[(size_t)col * 16 + ks * 4 + q];
            acc[ct] = __builtin_amdgcn_mfma_f32_16x16x32_bf16(a, b, acc[ct], 0, 0, 0);
        }
    }
#pragma unroll
    for (int ct = 0; ct < 16; ++ct) {
        int col = ct * 16 + r;
#pragma unroll
        for (int j = 0; j < 4; ++j) {
            int row = q * 4 + j;
            ftb[(size_t)(m0 + row) * C_OUT + col] = f2bf(acc[ct][j]);
        }
    }
}

// ---------------- per-node el2/er2 (all f32) ----------------
__global__ __launch_bounds__(256) void k_node2(const float* __restrict__ feat,
                                               const float* __restrict__ al1,
                                               const float* __restrict__ ar1,
                                               float* __restrict__ nl2, float* __restrict__ nr2) {
    __shared__ float s_al2[512], s_ar2[512];
    int t = threadIdx.x;
    for (int i = t; i < 512; i += 256) {
        float a = al1[i]; s_al2[i] = a * a;
        float b = ar1[i]; s_ar2[i] = b * b;
    }
    __syncthreads();
    int g = blockIdx.x * 256 + t;
    int n = g >> 2, h = g & 3;
    if (n >= N_NODES) return;
    const float4* f4 = (const float4*)feat;
    float accl = 0.f, accr = 0.f;
#pragma unroll 4
    for (int k = 0; k < 32; ++k) {
        float4 v = f4[(size_t)n * 32 + k];
        float p0 = v.x * v.x, p1 = v.y * v.y, p2 = v.z * v.z, p3 = v.w * v.w;
        const float* wl = &s_al2[h * 128 + k * 4];
        const float* wr = &s_ar2[h * 128 + k * 4];
        accl += p0 * wl[0] + p1 * wl[1] + p2 * wl[2] + p3 * wl[3];
        accr += p0 * wr[0] + p1 * wr[1] + p2 * wr[2] + p3 * wr[3];
    }
    nl2[g] = accl; nr2[g] = accr;
}

// ---------------- CSR build ----------------
__global__ void k_zero(int* __restrict__ deg) {
    int i = blockIdx.x * 256 + threadIdx.x;
    if (i < N_NODES) deg[i] = 0;
}
__global__ void k_deg(const int* __restrict__ dst, int* __restrict__ deg) {
    int e = blockIdx.x * 256 + threadIdx.x;
    if (e < N_EDGES) atomicAdd(&deg[dst[e]], 1);
}
__global__ __launch_bounds__(1024) void k_scan(const int* __restrict__ deg,
                                               int* __restrict__ off, int* __restrict__ fill) {
    __shared__ int s[1024];
    __shared__ int carry;
    int t = threadIdx.x;
    if (t == 0) carry = 0;
    __syncthreads();
    for (int base = 0; base < N_NODES; base += 1024) {
        int x = (base + t < N_NODES) ? deg[base + t] : 0;
        s[t] = x; __syncthreads();
        for (int o = 1; o < 1024; o <<= 1) {
            int v = (t >= o) ? s[t - o] : 0;
            __syncthreads();
            s[t] += v;
            __syncthreads();
        }
        int incl = s[t];
        int c = carry;
        if (base + t < N_NODES) {
            int ex = c + incl - x;
            off[base + t] = ex; fill[base + t] = ex;
        }
        __syncthreads();
        if (t == 1023) carry = c + s[1023];
        __syncthreads();
    }
    if (t == 0) off[N_NODES] = carry;
}
__global__ void k_scatter(const int* __restrict__ src, const int* __restrict__ dst,
                          int* __restrict__ fill, int2* __restrict__ srcdst) {
    int e = blockIdx.x * 256 + threadIdx.x;
    if (e >= N_EDGES) return;
    int d = dst[e];
    int pos = atomicAdd(&fill[d], 1);
    srcdst[pos] = make_int2(src[e], d);
}

// ---------------- edge scores in CSR order: 32 lanes per edge (f32) ----------------
__global__ __launch_bounds__(256) void k_edge(const float* __restrict__ feat,
                                              const float* __restrict__ al,
                                              const float* __restrict__ ar,
                                              const float* __restrict__ al1,
                                              const float* __restrict__ ar1,
                                              const int2* __restrict__ srcdst,
                                              const float* __restrict__ nl2,
                                              const float* __restrict__ nr2,
                                              float* __restrict__ escore) {
    __shared__ float we_s[512];   // combined weight al*ar - 2*al1*ar1, [h][128]
    int t = threadIdx.x;
    for (int i = t; i < 512; i += 256) {
        we_s[i] = al[i] * ar[i] - 2.0f * al1[i] * ar1[i];
    }
    __syncthreads();
    int lane = t & 63, l32 = lane & 31;
    int wave = blockIdx.x * 4 + (t >> 6);
    int edge = wave * 2 + (lane >> 5);      // grid sized exactly: E = 100000*8

    float we[4][4];
#pragma unroll
    for (int h = 0; h < 4; ++h) {
        const float4* p = (const float4*)&we_s[h * 128];
        float4 w = p[l32];
        we[h][0] = w.x; we[h][1] = w.y; we[h][2] = w.z; we[h][3] = w.w;
    }
    int2 sd = srcdst[edge];
    int s = sd.x, d = sd.y;
    const float4* f4 = (const float4*)feat;
    float4 vs = f4[(size_t)s * 32 + l32];
    float4 vd = f4[(size_t)d * 32 + l32];
    float p[4] = { vs.x * vd.x, vs.y * vd.y, vs.z * vd.z, vs.w * vd.w };
    float sh[4];
#pragma unroll
    for (int h = 0; h < 4; ++h) {
        float a = 0.f;
#pragma unroll
        for (int j = 0; j < 4; ++j) a += p[j] * we[h][j];
        sh[h] = a;
    }
#pragma unroll
    for (int m = 1; m < 32; m <<= 1) {
#pragma unroll
        for (int h = 0; h < 4; ++h) sh[h] += __shfl_xor(sh[h], m, 64);
    }
    if (l32 < 4) {
        float v = (l32 == 0) ? sh[0] : (l32 == 1) ? sh[1] : (l32 == 2) ? sh[2] : sh[3];
        escore[(size_t)edge * 4 + l32] = v + nl2[s * 4 + l32] + nr2[d * 4 + l32];
    }
}

// ---------------- per-dst softmax + aggregation (one block per node) ----------------
__global__ __launch_bounds__(256) void k_agg(const unsigned short* __restrict__ ftb,
                                             const float* __restrict__ escore,
                                             const int2* __restrict__ srcdst,
                                             const int* __restrict__ off,
                                             const float* __restrict__ bias,
                                             float* __restrict__ out) {
    int d = blockIdx.x;
    int t = threadIdx.x;
    int h = t >> 6;
    int beg = off[d], end = off[d + 1];
    int deg = end - beg;
    float bi = bias[t];
    if (deg == 0) { out[(size_t)d * C_OUT + t] = bi; return; }

    __shared__ float s_red[256];
    __shared__ float s_m[4], s_den[4];
    __shared__ float s_ex[256];
    __shared__ int   s_src[64];

    int h4 = t & 3, idx = t >> 2;
    float lm = -3.4e38f;
    for (int i = idx; i < deg; i += 64)
        lm = fmaxf(lm, escore[(size_t)(beg + i) * 4 + h4]);
    s_red[t] = lm; __syncthreads();
    for (int sN = 128; sN >= 4; sN >>= 1) {
        if (t < sN) s_red[t] = fmaxf(s_red[t], s_red[t + sN]);
        __syncthreads();
    }
    if (t < 4) s_m[t] = s_red[t];
    __syncthreads();

    float mh4 = s_m[h4];
    float ls = 0.f;
    for (int i = idx; i < deg; i += 64)
        ls += expf(escore[(size_t)(beg + i) * 4 + h4] - mh4);
    s_red[t] = ls; __syncthreads();
    for (int sN = 128; sN >= 4; sN >>= 1) {
        if (t < sN) s_red[t] += s_red[t + sN];
        __syncthreads();
    }
    if (t < 4) s_den[t] = s_red[t];

    float acc = 0.f;
    for (int c0 = 0; c0 < deg; c0 += 64) {
        int cn = min(64, deg - c0);
        __syncthreads();
        if (t < cn) s_src[t] = srcdst[beg + c0 + t].x;
        if (t < cn * 4) {
            int i = t >> 2, hh = t & 3;
            s_ex[t] = expf(escore[(size_t)(beg + c0 + i) * 4 + hh] - s_m[hh]);
        }
        __syncthreads();
        for (int i = 0; i < cn; ++i) {
            float a = s_ex[i * 4 + h];
            int s = s_src[i];
            acc += a * bf2f(ftb[(size_t)s * C_OUT + t]);
        }
    }
    float r = acc / s_den[h] + bi;
    out[(size_t)d * C_OUT + t] = r;
}

extern "C" void kernel_launch(void* const* d_in, const int* in_sizes, int n_in,
                              void* d_out, int out_size, void* d_ws, size_t ws_size,
                              hipStream_t stream) {
    const float* feat = (const float*)d_in[0];
    const int*   src  = (const int*)d_in[1];
    const int*   dst  = (const int*)d_in[2];
    const float* fcw  = (const float*)d_in[3];
    const float* al   = (const float*)d_in[4];
    const float* ar   = (const float*)d_in[5];
    const float* al1  = (const float*)d_in[6];
    const float* ar1  = (const float*)d_in[7];
    const float* bias = (const float*)d_in[8];
    float* out = (float*)d_out;

    char* ws = (char*)d_ws;
    size_t o = 0;
    auto take = [&](size_t b) -> void* {
        void* p = ws + o;
        o = (o + b + 255) & ~(size_t)255;
        return p;
    };
    unsigned short* fb16 = (unsigned short*)take((size_t)N_NODES * F_IN * 2);  // 12.8 MB
    unsigned short* wb16 = (unsigned short*)take((size_t)C_OUT * F_IN * 2);    // 64 KB
    unsigned short* ftb  = (unsigned short*)take((size_t)N_NODES * C_OUT * 2); // 25.6 MB
    float* escore = (float*)take((size_t)N_EDGES * 4 * 4);                     // 12.8 MB
    int2*  srcdst = (int2*)take((size_t)N_EDGES * 8);                          // 6.4 MB
    int*   deg    = (int*)take((size_t)N_NODES * 4);
    int*   off    = (int*)take((size_t)(N_NODES + 1) * 4);
    int*   fill   = (int*)take((size_t)N_NODES * 4);
    float* nl2    = (float*)take((size_t)N_NODES * 4 * 4);
    float* nr2    = (float*)take((size_t)N_NODES * 4 * 4);

    const int CVT_T = N_NODES * F_IN / 4 + C_OUT * F_IN / 4;   // 1,608,192
    k_zero<<<(N_NODES + 255) / 256, 256, 0, stream>>>(deg);
    k_cvt<<<(CVT_T + 255) / 256, 256, 0, stream>>>(feat, fcw, fb16, wb16);
    k_ft<<<782, 256, 0, stream>>>(fb16, wb16, ftb);
    k_node2<<<(N_NODES * 4 + 255) / 256, 256, 0, stream>>>(feat, al1, ar1, nl2, nr2);
    k_deg<<<(N_EDGES + 255) / 256, 256, 0, stream>>>(dst, deg);
    k_scan<<<1, 1024, 0, stream>>>(deg, off, fill);
    k_scatter<<<(N_EDGES + 255) / 256, 256, 0, stream>>>(src, dst, fill, srcdst);
    k_edge<<<N_EDGES / 8, 256, 0, stream>>>(feat, al, ar, al1, ar1, srcdst, nl2, nr2, escore);
    k_agg<<<N_NODES, 256, 0, stream>>>(ftb, escore, srcdst, off, bias, out);
}

// Round 3
// 450.295 us; speedup vs baseline: 1.2999x; 1.2999x over previous
//
#include <hip/hip_runtime.h>

#define N_NODES 50000
#define N_EDGES 800000
#define F_IN    128
#define NH      4
#define C_OUT   256   // NH*F_OUT

typedef short bf16x8 __attribute__((ext_vector_type(8)));
typedef float f32x4  __attribute__((ext_vector_type(4)));

__device__ __forceinline__ float bf2f(unsigned short u) {
    union { unsigned int i; float f; } v; v.i = ((unsigned int)u) << 16; return v.f;
}
__device__ __forceinline__ unsigned short f2bf(float f) {
    union { float f; unsigned int u; } v; v.f = f;
    return (unsigned short)((v.u + 0x7FFFu + ((v.u >> 16) & 1u)) >> 16);
}
__device__ __forceinline__ unsigned asu(float f) { union { float f; unsigned u; } v; v.f = f; return v.u; }
__device__ __forceinline__ float asf(unsigned u) { union { unsigned u; float f; } v; v.u = u; return v.f; }

// ------- fused: feat f32 -> bf16 copy + nl2[n,h] = sum_f feat^2 * al1^2 (er2 dropped: cancels in softmax)
__global__ __launch_bounds__(256) void k_prep(const float* __restrict__ feat,
                                              const float* __restrict__ al1,
                                              unsigned short* __restrict__ fb16,
                                              float* __restrict__ nl2) {
    __shared__ float s_w[512];
    int t = threadIdx.x;
    for (int i = t; i < 512; i += 256) { float a = al1[i]; s_w[i] = a * a; }
    __syncthreads();
    int g = blockIdx.x * 256 + t;
    int n = g >> 2, h = g & 3;
    if (n >= N_NODES) return;
    const float4* f4 = (const float4*)feat;
    uint2* fo = (uint2*)fb16;
    float acc = 0.f;
#pragma unroll 4
    for (int k = 0; k < 32; ++k) {
        float4 v = f4[(size_t)n * 32 + k];
        const float* w = &s_w[h * 128 + k * 4];
        acc += v.x * v.x * w[0] + v.y * v.y * w[1] + v.z * v.z * w[2] + v.w * v.w * w[3];
        if ((k >> 3) == h) {   // each of the 4 threads on this row writes its quarter
            unsigned lo = ((unsigned)f2bf(v.y) << 16) | f2bf(v.x);
            unsigned hi = ((unsigned)f2bf(v.w) << 16) | f2bf(v.z);
            fo[(size_t)n * 32 + k] = make_uint2(lo, hi);
        }
    }
    nl2[g] = acc;
}

// ------- fc_w f32 -> bf16
__global__ __launch_bounds__(256) void k_cvtw(const float* __restrict__ fcw,
                                              unsigned short* __restrict__ wb16) {
    int i = blockIdx.x * 256 + threadIdx.x;   // 8192 float4s
    float4 v = ((const float4*)fcw)[i];
    ushort4 o = { f2bf(v.x), f2bf(v.y), f2bf(v.z), f2bf(v.w) };
    ((ushort4*)wb16)[i] = o;
}

// ------- ft = feat @ fc_w.T (bf16 MFMA), M=50000, N=256, K=128
__global__ __launch_bounds__(256) void k_ft(const unsigned short* __restrict__ fb16,
                                            const unsigned short* __restrict__ wb16,
                                            unsigned short* __restrict__ ftb) {
    int t = threadIdx.x;
    int wave = blockIdx.x * 4 + (t >> 6);
    if (wave >= 3125) return;
    int lane = t & 63, r = lane & 15, q = lane >> 4;
    int m0 = wave * 16;
    f32x4 acc[16] = {};
    const bf16x8* A = (const bf16x8*)fb16;
    const bf16x8* B = (const bf16x8*)wb16;
#pragma unroll
    for (int ks = 0; ks < 4; ++ks) {
        bf16x8 a = A[(size_t)(m0 + r) * 16 + ks * 4 + q];
#pragma unroll
        for (int ct = 0; ct < 16; ++ct) {
            int col = ct * 16 + r;
            bf16x8 b = B[(size_t)col * 16 + ks * 4 + q];
            acc[ct] = __builtin_amdgcn_mfma_f32_16x16x32_bf16(a, b, acc[ct], 0, 0, 0);
        }
    }
#pragma unroll
    for (int ct = 0; ct < 16; ++ct) {
        int col = ct * 16 + r;
#pragma unroll
        for (int j = 0; j < 4; ++j)
            ftb[(size_t)(m0 + q * 4 + j) * C_OUT + col] = f2bf(acc[ct][j]);
    }
}

// ------- CSR build -------
__global__ void k_zero(int* __restrict__ deg) {
    int i = blockIdx.x * 256 + threadIdx.x;
    if (i < N_NODES) deg[i] = 0;
}
__global__ void k_deg(const int* __restrict__ dst, int* __restrict__ deg) {
    int e = blockIdx.x * 256 + threadIdx.x;
    if (e < N_EDGES) atomicAdd(&deg[dst[e]], 1);
}
__global__ __launch_bounds__(1024) void k_scan(const int* __restrict__ deg,
                                               int* __restrict__ off, int* __restrict__ fill) {
    __shared__ int s_wsum[16];
    __shared__ int s_carry;
    int t = threadIdx.x, w = t >> 6, l = t & 63;
    if (t == 0) s_carry = 0;
    __syncthreads();
    for (int base = 0; base < N_NODES; base += 1024) {
        int i = base + t;
        int x = (i < N_NODES) ? deg[i] : 0;
        int v = x;
#pragma unroll
        for (int o = 1; o < 64; o <<= 1) {
            int u = __shfl_up(v, o, 64);
            if (l >= o) v += u;
        }
        if (l == 63) s_wsum[w] = v;
        __syncthreads();
        int woff = 0;
#pragma unroll
        for (int j = 0; j < 16; ++j) woff += (j < w) ? s_wsum[j] : 0;
        int carry = s_carry;
        if (i < N_NODES) {
            int ex = carry + woff + v - x;
            off[i] = ex; fill[i] = ex;
        }
        __syncthreads();
        if (t == 1023) s_carry = carry + woff + v;
        __syncthreads();
    }
    if (t == 0) off[N_NODES] = s_carry;
}
__global__ void k_scatter(const int* __restrict__ src, const int* __restrict__ dst,
                          int* __restrict__ fill, int2* __restrict__ srcdst) {
    int e = blockIdx.x * 256 + threadIdx.x;
    if (e >= N_EDGES) return;
    int d = dst[e];
    int pos = atomicAdd(&fill[d], 1);
    srcdst[pos] = make_int2(src[e], d);
}

// ------- edge scores via MFMA: 16 edges/wave-batch, A = fs*fd (bf16), B = W (4 live cols)
__global__ __launch_bounds__(256) void k_edge(const unsigned short* __restrict__ fb16,
                                              const float* __restrict__ al, const float* __restrict__ ar,
                                              const float* __restrict__ al1, const float* __restrict__ ar1,
                                              const int2* __restrict__ srcdst,
                                              const float* __restrict__ nl2,
                                              float* __restrict__ escore) {
    __shared__ unsigned short s_w[512];   // W[h][f] bf16, h<4
    int t = threadIdx.x;
    for (int i = t; i < 512; i += 256)
        s_w[i] = f2bf(al[i] * ar[i] - 2.0f * al1[i] * ar1[i]);
    __syncthreads();
    int lane = t & 63, m = lane & 15, q = lane >> 4;
    int wave = blockIdx.x * 4 + (t >> 6);

    bf16x8 bw[4];
#pragma unroll
    for (int ks = 0; ks < 4; ++ks) {
        if (m < NH) bw[ks] = *(const bf16x8*)&s_w[m * 128 + ks * 32 + q * 8];
        else { bf16x8 z = {0, 0, 0, 0, 0, 0, 0, 0}; bw[ks] = z; }
    }
#pragma unroll
    for (int it = 0; it < 4; ++it) {
        int e0 = (wave * 4 + it) * 16;
        int2 sd = srcdst[e0 + m];
        const uint4* ps = (const uint4*)(fb16 + (size_t)sd.x * 128);
        const uint4* pd = (const uint4*)(fb16 + (size_t)sd.y * 128);
        f32x4 acc = {0.f, 0.f, 0.f, 0.f};
#pragma unroll
        for (int ks = 0; ks < 4; ++ks) {
            uint4 us = ps[ks * 4 + q];
            uint4 ud = pd[ks * 4 + q];
            unsigned c[4] = { us.x, us.y, us.z, us.w };
            unsigned dd[4] = { ud.x, ud.y, ud.z, ud.w };
            union { bf16x8 v; unsigned u[4]; } afr;
#pragma unroll
            for (int j = 0; j < 4; ++j) {
                float a0 = asf(c[j] << 16), a1 = asf(c[j] & 0xffff0000u);
                float b0 = asf(dd[j] << 16), b1 = asf(dd[j] & 0xffff0000u);
                float p0 = a0 * b0, p1 = a1 * b1;
                afr.u[j] = __builtin_amdgcn_perm(asu(p1), asu(p0), 0x07060302u);
            }
            acc = __builtin_amdgcn_mfma_f32_16x16x32_bf16(afr.v, bw[ks], acc, 0, 0, 0);
        }
        if (m < NH) {   // C layout: col=lane&15 (head), row=q*4+j (edge)
#pragma unroll
            for (int j = 0; j < 4; ++j) {
                int e = e0 + q * 4 + j;
                int s = srcdst[e].x;
                escore[(size_t)e * 4 + m] = acc[j] + nl2[s * 4 + m];
            }
        }
    }
}

// ------- per-dst softmax + aggregation: wave per edge-slice, uint2 ftb loads, fused denom
__global__ __launch_bounds__(256) void k_agg(const unsigned short* __restrict__ ftb,
                                             const float* __restrict__ escore,
                                             const int2* __restrict__ srcdst,
                                             const int* __restrict__ off,
                                             const float* __restrict__ bias,
                                             float* __restrict__ out) {
    int d = blockIdx.x, t = threadIdx.x;
    int w = t >> 6, lane = t & 63, h = lane >> 4;
    int beg = off[d], deg = off[d + 1] - beg;
    if (deg == 0) { out[(size_t)d * C_OUT + t] = bias[t]; return; }

    __shared__ float s_red[256];
    __shared__ float4 s_p4[256];   // [w][lane]
    __shared__ float s_den[16];    // [w][h]

    float mx = -3.4e38f;
    for (int i = w; i < deg; i += 4)
        mx = fmaxf(mx, escore[(size_t)(beg + i) * 4 + h]);
    s_red[t] = mx;
    __syncthreads();
    mx = fmaxf(fmaxf(s_red[lane], s_red[64 + lane]), fmaxf(s_red[128 + lane], s_red[192 + lane]));

    float acc0 = 0.f, acc1 = 0.f, acc2 = 0.f, acc3 = 0.f, den = 0.f;
    const uint2* fp = (const uint2*)ftb;
    for (int i = w; i < deg; i += 4) {
        float e = escore[(size_t)(beg + i) * 4 + h];
        float ex = __expf(e - mx);
        int s = srcdst[beg + i].x;
        uint2 u = fp[(size_t)s * 64 + lane];
        acc0 += ex * asf(u.x << 16);
        acc1 += ex * asf(u.x & 0xffff0000u);
        acc2 += ex * asf(u.y << 16);
        acc3 += ex * asf(u.y & 0xffff0000u);
        den += ex;
    }
    s_p4[w * 64 + lane] = make_float4(acc0, acc1, acc2, acc3);
    if ((lane & 15) == 0) s_den[w * 4 + h] = den;
    __syncthreads();
    const float* sp = (const float*)s_p4;
    float sum = sp[t] + sp[256 + t] + sp[512 + t] + sp[768 + t];
    int ho = t >> 6;
    float dn = s_den[ho] + s_den[4 + ho] + s_den[8 + ho] + s_den[12 + ho];
    out[(size_t)d * C_OUT + t] = sum / dn + bias[t];
}

extern "C" void kernel_launch(void* const* d_in, const int* in_sizes, int n_in,
                              void* d_out, int out_size, void* d_ws, size_t ws_size,
                              hipStream_t stream) {
    const float* feat = (const float*)d_in[0];
    const int*   src  = (const int*)d_in[1];
    const int*   dst  = (const int*)d_in[2];
    const float* fcw  = (const float*)d_in[3];
    const float* al   = (const float*)d_in[4];
    const float* ar   = (const float*)d_in[5];
    const float* al1  = (const float*)d_in[6];
    const float* ar1  = (const float*)d_in[7];
    const float* bias = (const float*)d_in[8];
    float* out = (float*)d_out;

    char* ws = (char*)d_ws;
    size_t o = 0;
    auto take = [&](size_t b) -> void* {
        void* p = ws + o;
        o = (o + b + 255) & ~(size_t)255;
        return p;
    };
    unsigned short* fb16 = (unsigned short*)take((size_t)N_NODES * F_IN * 2);  // 12.8 MB
    unsigned short* wb16 = (unsigned short*)take((size_t)C_OUT * F_IN * 2);    // 64 KB
    unsigned short* ftb  = (unsigned short*)take((size_t)N_NODES * C_OUT * 2); // 25.6 MB
    float* escore = (float*)take((size_t)N_EDGES * 4 * 4);                     // 12.8 MB
    int2*  srcdst = (int2*)take((size_t)N_EDGES * 8);                          // 6.4 MB
    int*   deg    = (int*)take((size_t)N_NODES * 4);
    int*   off    = (int*)take((size_t)(N_NODES + 1) * 4);
    int*   fill   = (int*)take((size_t)N_NODES * 4);
    float* nl2    = (float*)take((size_t)N_NODES * 4 * 4);

    k_zero<<<(N_NODES + 255) / 256, 256, 0, stream>>>(deg);
    k_prep<<<(N_NODES * 4 + 255) / 256, 256, 0, stream>>>(feat, al1, fb16, nl2);
    k_cvtw<<<32, 256, 0, stream>>>(fcw, wb16);
    k_ft<<<782, 256, 0, stream>>>(fb16, wb16, ftb);
    k_deg<<<(N_EDGES + 255) / 256, 256, 0, stream>>>(dst, deg);
    k_scan<<<1, 1024, 0, stream>>>(deg, off, fill);
    k_scatter<<<(N_EDGES + 255) / 256, 256, 0, stream>>>(src, dst, fill, srcdst);
    k_edge<<<3125, 256, 0, stream>>>(fb16, al, ar, al1, ar1, srcdst, nl2, escore);
    k_agg<<<N_NODES, 256, 0, stream>>>(ftb, escore, srcdst, off, bias, out);
}

// Round 4
// 388.931 us; speedup vs baseline: 1.5049x; 1.1578x over previous
//
#include <hip/hip_runtime.h>

#define N_NODES 50000
#define N_EDGES 800000
#define F_IN    128
#define NH      4
#define C_OUT   256   // NH*F_OUT

typedef short bf16x8 __attribute__((ext_vector_type(8)));
typedef float f32x4  __attribute__((ext_vector_type(4)));

__device__ __forceinline__ float bf2f(unsigned short u) {
    union { unsigned int i; float f; } v; v.i = ((unsigned int)u) << 16; return v.f;
}
__device__ __forceinline__ unsigned short f2bf(float f) {
    union { float f; unsigned int u; } v; v.f = f;
    return (unsigned short)((v.u + 0x7FFFu + ((v.u >> 16) & 1u)) >> 16);
}
__device__ __forceinline__ unsigned asu(float f) { union { float f; unsigned u; } v; v.f = f; return v.u; }
__device__ __forceinline__ float asf(unsigned u) { union { unsigned u; float f; } v; v.u = u; return v.f; }

// ------- fused: feat f32 -> bf16 copy + nl2[n,h] = sum_f feat^2 * al1^2 (er2 dropped: cancels in softmax)
__global__ __launch_bounds__(256) void k_prep(const float* __restrict__ feat,
                                              const float* __restrict__ al1,
                                              unsigned short* __restrict__ fb16,
                                              float* __restrict__ nl2) {
    __shared__ float s_w[512];
    int t = threadIdx.x;
    for (int i = t; i < 512; i += 256) { float a = al1[i]; s_w[i] = a * a; }
    __syncthreads();
    int g = blockIdx.x * 256 + t;
    int n = g >> 2, h = g & 3;
    if (n >= N_NODES) return;
    const float4* f4 = (const float4*)feat;
    uint2* fo = (uint2*)fb16;
    float acc = 0.f;
#pragma unroll 4
    for (int k = 0; k < 32; ++k) {
        float4 v = f4[(size_t)n * 32 + k];
        const float* w = &s_w[h * 128 + k * 4];
        acc += v.x * v.x * w[0] + v.y * v.y * w[1] + v.z * v.z * w[2] + v.w * v.w * w[3];
        if ((k >> 3) == h) {
            unsigned lo = ((unsigned)f2bf(v.y) << 16) | f2bf(v.x);
            unsigned hi = ((unsigned)f2bf(v.w) << 16) | f2bf(v.z);
            fo[(size_t)n * 32 + k] = make_uint2(lo, hi);
        }
    }
    nl2[g] = acc;
}

// ------- fc_w f32 -> bf16
__global__ __launch_bounds__(256) void k_cvtw(const float* __restrict__ fcw,
                                              unsigned short* __restrict__ wb16) {
    int i = blockIdx.x * 256 + threadIdx.x;
    float4 v = ((const float4*)fcw)[i];
    ushort4 o = { f2bf(v.x), f2bf(v.y), f2bf(v.z), f2bf(v.w) };
    ((ushort4*)wb16)[i] = o;
}

// ------- ft = feat @ fc_w.T (bf16 MFMA), M=50000, N=256, K=128
__global__ __launch_bounds__(256) void k_ft(const unsigned short* __restrict__ fb16,
                                            const unsigned short* __restrict__ wb16,
                                            unsigned short* __restrict__ ftb) {
    int t = threadIdx.x;
    int wave = blockIdx.x * 4 + (t >> 6);
    if (wave >= 3125) return;
    int lane = t & 63, r = lane & 15, q = lane >> 4;
    int m0 = wave * 16;
    f32x4 acc[16] = {};
    const bf16x8* A = (const bf16x8*)fb16;
    const bf16x8* B = (const bf16x8*)wb16;
#pragma unroll
    for (int ks = 0; ks < 4; ++ks) {
        bf16x8 a = A[(size_t)(m0 + r) * 16 + ks * 4 + q];
#pragma unroll
        for (int ct = 0; ct < 16; ++ct) {
            int col = ct * 16 + r;
            bf16x8 b = B[(size_t)col * 16 + ks * 4 + q];
            acc[ct] = __builtin_amdgcn_mfma_f32_16x16x32_bf16(a, b, acc[ct], 0, 0, 0);
        }
    }
#pragma unroll
    for (int ct = 0; ct < 16; ++ct) {
        int col = ct * 16 + r;
#pragma unroll
        for (int j = 0; j < 4; ++j)
            ftb[(size_t)(m0 + q * 4 + j) * C_OUT + col] = f2bf(acc[ct][j]);
    }
}

// ------- CSR build -------
__global__ void k_zero(int* __restrict__ deg) {
    int i = blockIdx.x * 256 + threadIdx.x;
    if (i < N_NODES) deg[i] = 0;
}
__global__ void k_deg(const int* __restrict__ dst, int* __restrict__ deg) {
    int e = blockIdx.x * 256 + threadIdx.x;
    if (e < N_EDGES) atomicAdd(&deg[dst[e]], 1);
}
__global__ __launch_bounds__(1024) void k_scan(const int* __restrict__ deg,
                                               int* __restrict__ off, int* __restrict__ fill) {
    __shared__ int s_wsum[16];
    __shared__ int s_carry;
    int t = threadIdx.x, w = t >> 6, l = t & 63;
    if (t == 0) s_carry = 0;
    __syncthreads();
    for (int base = 0; base < N_NODES; base += 1024) {
        int i = base + t;
        int x = (i < N_NODES) ? deg[i] : 0;
        int v = x;
#pragma unroll
        for (int o = 1; o < 64; o <<= 1) {
            int u = __shfl_up(v, o, 64);
            if (l >= o) v += u;
        }
        if (l == 63) s_wsum[w] = v;
        __syncthreads();
        int woff = 0;
#pragma unroll
        for (int j = 0; j < 16; ++j) woff += (j < w) ? s_wsum[j] : 0;
        int carry = s_carry;
        if (i < N_NODES) {
            int ex = carry + woff + v - x;
            off[i] = ex; fill[i] = ex;
        }
        __syncthreads();
        if (t == 1023) s_carry = carry + woff + v;
        __syncthreads();
    }
    if (t == 0) off[N_NODES] = s_carry;
}
__global__ void k_scatter(const int* __restrict__ src, const int* __restrict__ dst,
                          int* __restrict__ fill, int2* __restrict__ srcdst) {
    int e = blockIdx.x * 256 + threadIdx.x;
    if (e >= N_EDGES) return;
    int d = dst[e];
    int pos = atomicAdd(&fill[d], 1);
    srcdst[pos] = make_int2(src[e], d);
}

// ------- edge scores via MFMA: 16 edges/wave-batch, A = fs*fd (bf16), B = W (4 live cols)
__global__ __launch_bounds__(256) void k_edge(const unsigned short* __restrict__ fb16,
                                              const float* __restrict__ al, const float* __restrict__ ar,
                                              const float* __restrict__ al1, const float* __restrict__ ar1,
                                              const int2* __restrict__ srcdst,
                                              const float* __restrict__ nl2,
                                              float* __restrict__ escore) {
    __shared__ unsigned short s_w[512];
    int t = threadIdx.x;
    for (int i = t; i < 512; i += 256)
        s_w[i] = f2bf(al[i] * ar[i] - 2.0f * al1[i] * ar1[i]);
    __syncthreads();
    int lane = t & 63, m = lane & 15, q = lane >> 4;
    int wave = blockIdx.x * 4 + (t >> 6);

    bf16x8 bw[4];
#pragma unroll
    for (int ks = 0; ks < 4; ++ks) {
        if (m < NH) bw[ks] = *(const bf16x8*)&s_w[m * 128 + ks * 32 + q * 8];
        else { bf16x8 z = {0, 0, 0, 0, 0, 0, 0, 0}; bw[ks] = z; }
    }
#pragma unroll
    for (int it = 0; it < 4; ++it) {
        int e0 = (wave * 4 + it) * 16;
        int2 sd = srcdst[e0 + m];
        const uint4* ps = (const uint4*)(fb16 + (size_t)sd.x * 128);
        const uint4* pd = (const uint4*)(fb16 + (size_t)sd.y * 128);
        f32x4 acc = {0.f, 0.f, 0.f, 0.f};
#pragma unroll
        for (int ks = 0; ks < 4; ++ks) {
            uint4 us = ps[ks * 4 + q];
            uint4 ud = pd[ks * 4 + q];
            unsigned c[4] = { us.x, us.y, us.z, us.w };
            unsigned dd[4] = { ud.x, ud.y, ud.z, ud.w };
            union { bf16x8 v; unsigned u[4]; } afr;
#pragma unroll
            for (int j = 0; j < 4; ++j) {
                float a0 = asf(c[j] << 16), a1 = asf(c[j] & 0xffff0000u);
                float b0 = asf(dd[j] << 16), b1 = asf(dd[j] & 0xffff0000u);
                float p0 = a0 * b0, p1 = a1 * b1;
                afr.u[j] = __builtin_amdgcn_perm(asu(p1), asu(p0), 0x07060302u);
            }
            acc = __builtin_amdgcn_mfma_f32_16x16x32_bf16(afr.v, bw[ks], acc, 0, 0, 0);
        }
        if (m < NH) {
#pragma unroll
            for (int j = 0; j < 4; ++j) {
                int e = e0 + q * 4 + j;
                int s = srcdst[e].x;
                escore[(size_t)e * 4 + m] = acc[j] + nl2[s * 4 + m];
            }
        }
    }
}

// ------- per-dst softmax + aggregation: WAVE PER NODE, 8-edge batches, no LDS/barriers
__global__ __launch_bounds__(256) void k_agg(const unsigned short* __restrict__ ftb,
                                             const float* __restrict__ escore,
                                             const int2* __restrict__ srcdst,
                                             const int* __restrict__ off,
                                             const float* __restrict__ bias,
                                             float* __restrict__ out) {
    int t = threadIdx.x;
    int l = t & 63;
    int d = blockIdx.x * 4 + (t >> 6);   // grid = 12500 exactly
    int hq = l >> 4;                     // head of output cols l*4..l*4+3
    int beg = off[d], deg = off[d + 1] - beg;

    float4 b4 = ((const float4*)bias)[l];
    if (deg == 0) { ((float4*)out)[(size_t)d * 64 + l] = b4; return; }

    // max over segment, per head: lane covers (edge i = l>>2 mod 16 stride, head l&3)
    float m = -3.4e38f;
    for (int i = l >> 2; i < deg; i += 16)
        m = fmaxf(m, escore[(size_t)(beg + i) * 4 + (l & 3)]);
#pragma unroll
    for (int mk = 4; mk < 64; mk <<= 1)
        m = fmaxf(m, __shfl_xor(m, mk, 64));
    float mh = __shfl(m, hq, 64);        // lane hq holds head hq's max

    float a0 = 0.f, a1 = 0.f, a2 = 0.f, a3 = 0.f, den = 0.f;
    const uint2* fp = (const uint2*)ftb;
    const int UN = 8;
    for (int j0 = 0; j0 < deg; j0 += UN) {
        int   sj[UN]; float ej[UN];
#pragma unroll
        for (int k = 0; k < UN; ++k) {
            int j = j0 + k; if (j > deg - 1) j = deg - 1;
            sj[k] = srcdst[beg + j].x;
            ej[k] = escore[(size_t)(beg + j) * 4 + hq];
        }
        uint2 uj[UN];
#pragma unroll
        for (int k = 0; k < UN; ++k)
            uj[k] = fp[(size_t)sj[k] * 64 + l];
#pragma unroll
        for (int k = 0; k < UN; ++k) {
            float ex = (j0 + k < deg) ? __expf(ej[k] - mh) : 0.f;
            den += ex;
            a0 += ex * asf(uj[k].x << 16);
            a1 += ex * asf(uj[k].x & 0xffff0000u);
            a2 += ex * asf(uj[k].y << 16);
            a3 += ex * asf(uj[k].y & 0xffff0000u);
        }
    }
    float inv = 1.0f / den;
    float4 o = make_float4(a0 * inv + b4.x, a1 * inv + b4.y, a2 * inv + b4.z, a3 * inv + b4.w);
    ((float4*)out)[(size_t)d * 64 + l] = o;
}

extern "C" void kernel_launch(void* const* d_in, const int* in_sizes, int n_in,
                              void* d_out, int out_size, void* d_ws, size_t ws_size,
                              hipStream_t stream) {
    const float* feat = (const float*)d_in[0];
    const int*   src  = (const int*)d_in[1];
    const int*   dst  = (const int*)d_in[2];
    const float* fcw  = (const float*)d_in[3];
    const float* al   = (const float*)d_in[4];
    const float* ar   = (const float*)d_in[5];
    const float* al1  = (const float*)d_in[6];
    const float* ar1  = (const float*)d_in[7];
    const float* bias = (const float*)d_in[8];
    float* out = (float*)d_out;

    char* ws = (char*)d_ws;
    size_t o = 0;
    auto take = [&](size_t b) -> void* {
        void* p = ws + o;
        o = (o + b + 255) & ~(size_t)255;
        return p;
    };
    unsigned short* fb16 = (unsigned short*)take((size_t)N_NODES * F_IN * 2);
    unsigned short* wb16 = (unsigned short*)take((size_t)C_OUT * F_IN * 2);
    unsigned short* ftb  = (unsigned short*)take((size_t)N_NODES * C_OUT * 2);
    float* escore = (float*)take((size_t)N_EDGES * 4 * 4);
    int2*  srcdst = (int2*)take((size_t)N_EDGES * 8);
    int*   deg    = (int*)take((size_t)N_NODES * 4);
    int*   off    = (int*)take((size_t)(N_NODES + 1) * 4);
    int*   fill   = (int*)take((size_t)N_NODES * 4);
    float* nl2    = (float*)take((size_t)N_NODES * 4 * 4);

    k_zero<<<(N_NODES + 255) / 256, 256, 0, stream>>>(deg);
    k_prep<<<(N_NODES * 4 + 255) / 256, 256, 0, stream>>>(feat, al1, fb16, nl2);
    k_cvtw<<<32, 256, 0, stream>>>(fcw, wb16);
    k_ft<<<782, 256, 0, stream>>>(fb16, wb16, ftb);
    k_deg<<<(N_EDGES + 255) / 256, 256, 0, stream>>>(dst, deg);
    k_scan<<<1, 1024, 0, stream>>>(deg, off, fill);
    k_scatter<<<(N_EDGES + 255) / 256, 256, 0, stream>>>(src, dst, fill, srcdst);
    k_edge<<<3125, 256, 0, stream>>>(fb16, al, ar, al1, ar1, srcdst, nl2, escore);
    k_agg<<<N_NODES / 4, 256, 0, stream>>>(ftb, escore, srcdst, off, bias, out);
}

// Round 5
// 381.287 us; speedup vs baseline: 1.5351x; 1.0200x over previous
//
#include <hip/hip_runtime.h>

#define N_NODES 50000
#define N_EDGES 800000
#define F_IN    128
#define NH      4
#define C_OUT   256   // NH*F_OUT

typedef short bf16x8 __attribute__((ext_vector_type(8)));
typedef float f32x4  __attribute__((ext_vector_type(4)));

__device__ __forceinline__ unsigned short f2bf(float f) {
    union { float f; unsigned int u; } v; v.f = f;
    return (unsigned short)((v.u + 0x7FFFu + ((v.u >> 16) & 1u)) >> 16);
}
__device__ __forceinline__ float asf(unsigned u) { union { unsigned u; float f; } v; v.u = u; return v.f; }

__device__ __forceinline__ void unp8(uint4 u, float* f) {
    f[0] = asf(u.x << 16); f[1] = asf(u.x & 0xffff0000u);
    f[2] = asf(u.y << 16); f[3] = asf(u.y & 0xffff0000u);
    f[4] = asf(u.z << 16); f[5] = asf(u.z & 0xffff0000u);
    f[6] = asf(u.w << 16); f[7] = asf(u.w & 0xffff0000u);
}

// ------- f32 -> bf16 conversion of feat and fc_w -------
__global__ __launch_bounds__(256) void k_cvt(const float* __restrict__ feat,
                                             const float* __restrict__ fcw,
                                             unsigned short* __restrict__ fb16,
                                             unsigned short* __restrict__ wb16) {
    int i = blockIdx.x * 256 + threadIdx.x;
    const int NF = N_NODES * F_IN / 4;        // 1,600,000
    const int NW = C_OUT * F_IN / 4;          // 8,192
    if (i < NF) {
        float4 v = ((const float4*)feat)[i];
        ushort4 o = { f2bf(v.x), f2bf(v.y), f2bf(v.z), f2bf(v.w) };
        ((ushort4*)fb16)[i] = o;
    } else if (i < NF + NW) {
        int j = i - NF;
        float4 v = ((const float4*)fcw)[j];
        ushort4 o = { f2bf(v.x), f2bf(v.y), f2bf(v.z), f2bf(v.w) };
        ((ushort4*)wb16)[j] = o;
    }
}

// ------- CSR build -------
__global__ void k_zero(int* __restrict__ deg) {
    int i = blockIdx.x * 256 + threadIdx.x;
    if (i < N_NODES) deg[i] = 0;
}
__global__ void k_deg(const int* __restrict__ dst, int* __restrict__ deg) {
    int e = blockIdx.x * 256 + threadIdx.x;
    if (e < N_EDGES) atomicAdd(&deg[dst[e]], 1);
}
__global__ __launch_bounds__(1024) void k_scan(const int* __restrict__ deg,
                                               int* __restrict__ off, int* __restrict__ fill) {
    __shared__ int s_wsum[16];
    __shared__ int s_carry;
    int t = threadIdx.x, w = t >> 6, l = t & 63;
    if (t == 0) s_carry = 0;
    __syncthreads();
    for (int base = 0; base < N_NODES; base += 1024) {
        int i = base + t;
        int x = (i < N_NODES) ? deg[i] : 0;
        int v = x;
#pragma unroll
        for (int o = 1; o < 64; o <<= 1) {
            int u = __shfl_up(v, o, 64);
            if (l >= o) v += u;
        }
        if (l == 63) s_wsum[w] = v;
        __syncthreads();
        int woff = 0;
#pragma unroll
        for (int j = 0; j < 16; ++j) woff += (j < w) ? s_wsum[j] : 0;
        int carry = s_carry;
        if (i < N_NODES) {
            int ex = carry + woff + v - x;
            off[i] = ex; fill[i] = ex;
        }
        __syncthreads();
        if (t == 1023) s_carry = carry + woff + v;
        __syncthreads();
    }
    if (t == 0) off[N_NODES] = s_carry;
}
__global__ void k_scatter(const int* __restrict__ src, const int* __restrict__ dst,
                          int* __restrict__ fill, int* __restrict__ esrc) {
    int e = blockIdx.x * 256 + threadIdx.x;
    if (e >= N_EDGES) return;
    int d = dst[e];
    int pos = atomicAdd(&fill[d], 1);
    esrc[pos] = src[e];
}

// ------- fused: edge scores + online softmax + feat-domain aggregation + MFMA projection
// wave per node (4 nodes/block). Lane l: head h=l&3, col-block cb=l>>2 (8 feat cols).
__global__ __launch_bounds__(256) void k_fused(const unsigned short* __restrict__ fb16,
                                               const unsigned short* __restrict__ wb16,
                                               const float* __restrict__ al, const float* __restrict__ ar,
                                               const float* __restrict__ al1, const float* __restrict__ ar1,
                                               const int* __restrict__ esrc,
                                               const int* __restrict__ off,
                                               const float* __restrict__ bias,
                                               float* __restrict__ out) {
    __shared__ float s_w2[512];               // al*ar - 2*al1*ar1, [h][128]
    __shared__ float s_wl2[512];              // al1^2, [h][128]
    __shared__ float s_bias[256];
    __shared__ unsigned short s_af[16 * 136]; // A-tile: 16 rows (node*4+h) x 128 k, pad 8

    int t = threadIdx.x;
    for (int i = t; i < 512; i += 256) {
        s_w2[i]  = al[i] * ar[i] - 2.0f * al1[i] * ar1[i];
        s_wl2[i] = al1[i] * al1[i];
    }
    s_bias[t] = bias[t];
    __syncthreads();

    int w = t >> 6, l = t & 63, h = l & 3, cb = l >> 2;
    int d = blockIdx.x * 4 + w;
    int beg = off[d], deg = off[d + 1] - beg;

    // per-lane weights and dst-row slice
    float w2[8], wl2[8], fd[8], tt[8];
#pragma unroll
    for (int j = 0; j < 8; ++j) {
        w2[j]  = s_w2[h * 128 + cb * 8 + j];
        wl2[j] = s_wl2[h * 128 + cb * 8 + j];
    }
    uint4 ud = ((const uint4*)fb16)[(size_t)d * 16 + cb];
    unp8(ud, fd);
#pragma unroll
    for (int j = 0; j < 8; ++j) tt[j] = fd[j] * w2[j];

    float m = -3.4e38f, den = 0.f;
    float acc[8] = {0.f, 0.f, 0.f, 0.f, 0.f, 0.f, 0.f, 0.f};

    for (int j0 = 0; j0 < deg; j0 += 4) {
        int idx[4];
#pragma unroll
        for (int k = 0; k < 4; ++k) {
            int j = j0 + k; if (j > deg - 1) j = deg - 1;
            idx[k] = esrc[beg + j];
        }
        uint4 u[4];
#pragma unroll
        for (int k = 0; k < 4; ++k)
            u[k] = ((const uint4*)fb16)[(size_t)idx[k] * 16 + cb];
        float fs[4][8], s[4];
#pragma unroll
        for (int k = 0; k < 4; ++k) {
            unp8(u[k], fs[k]);
            float p = 0.f;
#pragma unroll
            for (int j = 0; j < 8; ++j) {
                float v1 = fmaf(fs[k][j], wl2[j], tt[j]);   // fd*w2 + fs*al1^2
                p = fmaf(fs[k][j], v1, p);
            }
#pragma unroll
            for (int mk = 4; mk < 64; mk <<= 1)
                p += __shfl_xor(p, mk, 64);
            s[k] = p;
        }
        float mb = fmaxf(fmaxf(s[0], s[1]), fmaxf(s[2], s[3]));
        float mn = fmaxf(m, mb);
        float sc = __expf(m - mn);
        den *= sc;
#pragma unroll
        for (int j = 0; j < 8; ++j) acc[j] *= sc;
#pragma unroll
        for (int k = 0; k < 4; ++k) {
            float ex = (j0 + k < deg) ? __expf(s[k] - mn) : 0.f;
            den += ex;
#pragma unroll
            for (int j = 0; j < 8; ++j) acc[j] = fmaf(ex, fs[k][j], acc[j]);
        }
        m = mn;
    }

    float inv = (den > 0.f) ? 1.0f / den : 0.f;
    // write normalized aggregated features (bf16) to LDS A-tile, row = w*4+h
    {
        unsigned o0 = ((unsigned)f2bf(acc[1] * inv) << 16) | f2bf(acc[0] * inv);
        unsigned o1 = ((unsigned)f2bf(acc[3] * inv) << 16) | f2bf(acc[2] * inv);
        unsigned o2 = ((unsigned)f2bf(acc[5] * inv) << 16) | f2bf(acc[4] * inv);
        unsigned o3 = ((unsigned)f2bf(acc[7] * inv) << 16) | f2bf(acc[6] * inv);
        *(uint4*)&s_af[(w * 4 + h) * 136 + cb * 8] = make_uint4(o0, o1, o2, o3);
    }
    __syncthreads();

    // epilogue: C[16 nodes*heads][64 fout per head] via per-head MFMA; wave w owns col-tile w
    int n = l & 15, q = l >> 4;
    bf16x8 afr[4];
#pragma unroll
    for (int step = 0; step < 4; ++step)
        afr[step] = *(const bf16x8*)&s_af[n * 136 + step * 32 + q * 8];

    f32x4 c[4] = {};
#pragma unroll
    for (int h4 = 0; h4 < 4; ++h4) {
#pragma unroll
        for (int step = 0; step < 4; ++step) {
            union { uint4 u; bf16x8 v; } b;
            b.u = *(const uint4*)(wb16 + (size_t)(h4 * 64 + w * 16 + n) * 128 + step * 32 + q * 8);
            c[h4] = __builtin_amdgcn_mfma_f32_16x16x32_bf16(afr[step], b.v, c[h4], 0, 0, 0);
        }
    }
    int node = blockIdx.x * 4 + q;   // C row = q*4+j; keep j=h4 -> node q, head h4
#pragma unroll
    for (int h4 = 0; h4 < 4; ++h4)
        out[(size_t)node * 256 + h4 * 64 + w * 16 + n] = c[h4][h4] + s_bias[h4 * 64 + w * 16 + n];
}

extern "C" void kernel_launch(void* const* d_in, const int* in_sizes, int n_in,
                              void* d_out, int out_size, void* d_ws, size_t ws_size,
                              hipStream_t stream) {
    const float* feat = (const float*)d_in[0];
    const int*   src  = (const int*)d_in[1];
    const int*   dst  = (const int*)d_in[2];
    const float* fcw  = (const float*)d_in[3];
    const float* al   = (const float*)d_in[4];
    const float* ar   = (const float*)d_in[5];
    const float* al1  = (const float*)d_in[6];
    const float* ar1  = (const float*)d_in[7];
    const float* bias = (const float*)d_in[8];
    float* out = (float*)d_out;

    char* ws = (char*)d_ws;
    size_t o = 0;
    auto take = [&](size_t b) -> void* {
        void* p = ws + o;
        o = (o + b + 255) & ~(size_t)255;
        return p;
    };
    unsigned short* fb16 = (unsigned short*)take((size_t)N_NODES * F_IN * 2);  // 12.8 MB
    unsigned short* wb16 = (unsigned short*)take((size_t)C_OUT * F_IN * 2);    // 64 KB
    int* esrc = (int*)take((size_t)N_EDGES * 4);                               // 3.2 MB
    int* deg  = (int*)take((size_t)N_NODES * 4);
    int* off  = (int*)take((size_t)(N_NODES + 1) * 4);
    int* fill = (int*)take((size_t)N_NODES * 4);

    const int CVT_T = N_NODES * F_IN / 4 + C_OUT * F_IN / 4;
    k_zero<<<(N_NODES + 255) / 256, 256, 0, stream>>>(deg);
    k_cvt<<<(CVT_T + 255) / 256, 256, 0, stream>>>(feat, fcw, fb16, wb16);
    k_deg<<<(N_EDGES + 255) / 256, 256, 0, stream>>>(dst, deg);
    k_scan<<<1, 1024, 0, stream>>>(deg, off, fill);
    k_scatter<<<(N_EDGES + 255) / 256, 256, 0, stream>>>(src, dst, fill, esrc);
    k_fused<<<N_NODES / 4, 256, 0, stream>>>(fb16, wb16, al, ar, al1, ar1, esrc, off, bias, out);
}